// Round 4
// baseline (526.265 us; speedup 1.0000x reference)
//
#include <hip/hip_runtime.h>

// GenLSTM: B=8192, T=256 (255 steps), noise=8, seq_dim=4, HID=64, gates=256.
// R4 = R3 with cvt_pkrtz type fix (__fp16 vec2, not _Float16 vec2).
// Design: 256 blocks x 4 waves, M=32 rows/block (2 row-groups per wave, ILP).
// Swapped-operand MFMA (weights as A, state as B) computes C^T: each lane
// holds 4 consecutive output cols of one batch row -> packed b64 LDS writes
// (2 cvt_pkrtz + 1 ds_write_b64) and dwordx4 out-stores. u-layout is
// [h(64)|x(4)|noise(8)|pad]: a0/a1 pure-h from shared LDS, a2 (x|noise) from
// a WAVE-PRIVATE staging buffer (same-wave DS ordering, no barrier). Every
// wave computes the tiny x-phase redundantly -> no wave0 serialization, and
// barrier count drops 4 -> 3 per step. Weights stay in VGPRs (72 regs).

typedef _Float16 h8 __attribute__((ext_vector_type(8)));
typedef __fp16 p2h __attribute__((ext_vector_type(2)));   // cvt_pkrtz result type
typedef float f4 __attribute__((ext_vector_type(4)));

#define MFMA(a, b, c) __builtin_amdgcn_mfma_f32_16x16x32_f16(a, b, c, 0, 0, 0)

constexpr int SEQ = 256, STEPS = 255, ND = 8, SD = 4, HID = 64, G4 = 256;
constexpr int HST  = 72;  // h/y row stride (f16): 16B-aligned rows, 2-way banks
constexpr int A2ST = 24;  // wave-private a2 staging row stride (48B rows)

__device__ __forceinline__ float sigf(float x) {
    return __builtin_amdgcn_rcpf(1.0f + __expf(-x));
}
__device__ __forceinline__ float tanh_(float x) {
    return 2.0f * __builtin_amdgcn_rcpf(1.0f + __expf(-2.0f * x)) - 1.0f;
}
// pack 4 fp32 -> 4 fp16, one ds_write_b64
__device__ __forceinline__ void store4h(_Float16* p, f4 v) {
    p2h lo = __builtin_amdgcn_cvt_pkrtz(v[0], v[1]);
    p2h hi = __builtin_amdgcn_cvt_pkrtz(v[2], v[3]);
    float2 st;
    st.x = __builtin_bit_cast(float, lo);
    st.y = __builtin_bit_cast(float, hi);
    *(float2*)p = st;
}
// pack 2 fp32 -> 2 fp16, one ds_write_b32
__device__ __forceinline__ void store2h(_Float16* p, float a, float b_) {
    p2h v = __builtin_amdgcn_cvt_pkrtz(a, b_);
    *(float*)p = __builtin_bit_cast(float, v);
}

__global__ __launch_bounds__(256, 1) void genlstm_kernel(
    const float* __restrict__ noise, const float* __restrict__ Wx,
    const float* __restrict__ Wh, const float* __restrict__ b,
    const float* __restrict__ W1, const float* __restrict__ b1,
    const float* __restrict__ W2, const float* __restrict__ b2,
    const float* __restrict__ W3, const float* __restrict__ b3,
    float* __restrict__ out)
{
    __shared__ alignas(16) _Float16 Hb[2 * 2 * 16 * HST];   // [pb][g][row][HST]
    __shared__ alignas(16) _Float16 Y1b[2 * 16 * HST];      // [g][row][HST]
    __shared__ alignas(16) _Float16 Y2b[2 * 16 * HST];
    __shared__ alignas(16) _Float16 A2b[4 * 2 * 16 * A2ST]; // [wid][g][row][A2ST]
    __shared__ alignas(16) _Float16 Zb[8];                  // zeros for a2 quads 2/3

    const int tid = threadIdx.x, wid = tid >> 6, lane = tid & 63;
    const int col = lane & 15, quad = lane >> 4, q8 = quad * 8;
    const int row0 = blockIdx.x * 32;
    const int n0 = wid * 16 + col;
    const int mrow = quad * 4;           // output-row base in C^T layout
    const int wq = wid * 16 + mrow;      // packed-write col offset in h/y rows

    // ---- weight frags -> VGPRs (content identical to B-frags; used as A) ----
    // combined u-major weight: k<64 -> Wh, 64<=k<76 -> Wx (x rows 0..3, noise 4..11)
    h8 wg[4][3], w1f[2], w2f[2], w3f[2];
    #pragma unroll
    for (int g = 0; g < 4; ++g)
        #pragma unroll
        for (int s = 0; s < 3; ++s)
            #pragma unroll
            for (int j = 0; j < 8; ++j) {
                const int k = 32 * s + q8 + j;
                const int n = 64 * g + n0;
                float v;
                if (k < 64) v = Wh[k * G4 + n];
                else if (k < 76) v = Wx[(k - 64) * G4 + n];
                else v = 0.0f;
                wg[g][s][j] = (_Float16)v;
            }
    #pragma unroll
    for (int s = 0; s < 2; ++s)
        #pragma unroll
        for (int j = 0; j < 8; ++j) {
            const int k = 32 * s + q8 + j;
            w1f[s][j] = (_Float16)W1[k * HID + n0];
            w2f[s][j] = (_Float16)W2[k * HID + n0];
            w3f[s][j] = (_Float16)(col < 4 ? W3[k * SD + col] : 0.0f);
        }
    // biases indexed by OUTPUT row m' = 16*wid + quad*4 + r (C^T layout)
    f4 bzv[4], b1v, b2v, b3v;
    #pragma unroll
    for (int r = 0; r < 4; ++r) {
        #pragma unroll
        for (int g = 0; g < 4; ++g) bzv[g][r] = b[64 * g + wq + r];
        b1v[r] = b1[wq + r];
        b2v[r] = b2[wq + r];
        b3v[r] = (quad == 0) ? b3[r] : 0.0f;
    }

    // ---- LDS init: h0 = 0, a2 staging (x=0, pads=0), zero block ----
    for (int i = tid; i < 2 * 2 * 16 * HST; i += 256) Hb[i] = (_Float16)0;
    for (int i = tid; i < 4 * 2 * 16 * A2ST; i += 256) A2b[i] = (_Float16)0;
    if (tid < 8) Zb[tid] = (_Float16)0;
    if (tid < 32) {  // out[:, 0, :] = 0 (cumsum starts at x0 = 0)
        float4 z; z.x = z.y = z.z = z.w = 0.0f;
        *(float4*)(out + (size_t)(row0 + tid) * SEQ * SD) = z;
    }
    __syncthreads();

    // ---- loop-invariant pointers ----
    const int nrow = lane >> 2, ncc = (lane & 3) * 2;
    const float* nptr[2];
    _Float16* a2n[2];   // noise slot in own staging
    _Float16* a2x[2];   // x slot in own staging (quad0 lanes)
    const _Float16* a2rd[2];
    _Float16* Hrow[2][2];
    _Float16* Y1row[2];
    _Float16* Y2row[2];
    float* outp[2];
    #pragma unroll
    for (int g = 0; g < 2; ++g) {
        nptr[g] = noise + ((size_t)(row0 + 16 * g + nrow) * SEQ) * ND + ncc;
        a2n[g] = &A2b[((wid * 2 + g) * 16 + nrow) * A2ST + 4 + ncc];
        a2x[g] = &A2b[((wid * 2 + g) * 16 + col) * A2ST];
        a2rd[g] = (quad < 2) ? &A2b[((wid * 2 + g) * 16 + col) * A2ST + 8 * quad] : Zb;
        Y1row[g] = &Y1b[(g * 16 + col) * HST];
        Y2row[g] = &Y2b[(g * 16 + col) * HST];
        outp[g] = out + ((size_t)(row0 + 16 * g + col) * SEQ + 1) * SD;
        #pragma unroll
        for (int pb = 0; pb < 2; ++pb)
            Hrow[pb][g] = &Hb[((pb * 2 + g) * 16 + col) * HST];
    }
    // stage noise(t=0) into own buffer (wave-private, no barrier needed)
    #pragma unroll
    for (int g = 0; g < 2; ++g) {
        float2 nz = *(const float2*)nptr[g];
        store2h(a2n[g], nz.x, nz.y);
        nptr[g] += ND;
    }

    f4 cst[2], run[2];
    #pragma unroll
    for (int g = 0; g < 2; ++g)
        #pragma unroll
        for (int r = 0; r < 4; ++r) { cst[g][r] = 0.0f; run[g][r] = 0.0f; }

    auto body = [&](int pb) {
        // prefetch next step's noise (long-latency, hide under MFMA)
        float2 nz0 = *(const float2*)nptr[0];
        float2 nz1 = *(const float2*)nptr[1];
        nptr[0] += ND; nptr[1] += ND;

        // ---- gates + cell update, both groups ----
        #pragma unroll
        for (int g = 0; g < 2; ++g) {
            const _Float16* hr = Hrow[pb][g];
            h8 a0 = *(const h8*)(hr + q8);
            h8 a1 = *(const h8*)(hr + 32 + q8);
            h8 a2 = *(const h8*)(a2rd[g]);
            f4 zi = bzv[0], zf = bzv[1], zg = bzv[2], zo = bzv[3];
            zi = MFMA(wg[0][0], a0, zi); zi = MFMA(wg[0][1], a1, zi); zi = MFMA(wg[0][2], a2, zi);
            zf = MFMA(wg[1][0], a0, zf); zf = MFMA(wg[1][1], a1, zf); zf = MFMA(wg[1][2], a2, zf);
            zg = MFMA(wg[2][0], a0, zg); zg = MFMA(wg[2][1], a1, zg); zg = MFMA(wg[2][2], a2, zg);
            zo = MFMA(wg[3][0], a0, zo); zo = MFMA(wg[3][1], a1, zo); zo = MFMA(wg[3][2], a2, zo);
            f4 hv;
            #pragma unroll
            for (int r = 0; r < 4; ++r) {
                float I = sigf(zi[r]), F = sigf(zf[r]);
                float G = tanh_(zg[r]), O = sigf(zo[r]);
                float cn = F * cst[g][r] + I * G;
                cst[g][r] = cn;
                hv[r] = O * tanh_(cn);
            }
            store4h(Hrow[pb ^ 1][g] + wq, hv);  // h(t+1), packed b64
        }
        __syncthreads();  // B1: h(t+1) visible

        // ---- y1 = relu(h @ W1 + b1) ----
        #pragma unroll
        for (int g = 0; g < 2; ++g) {
            const _Float16* hr = Hrow[pb ^ 1][g];
            h8 h0 = *(const h8*)(hr + q8);
            h8 h1 = *(const h8*)(hr + 32 + q8);
            f4 y = b1v;
            y = MFMA(w1f[0], h0, y);
            y = MFMA(w1f[1], h1, y);
            #pragma unroll
            for (int r = 0; r < 4; ++r) y[r] = fmaxf(y[r], 0.0f);
            store4h(Y1row[g] + wq, y);
        }
        __syncthreads();  // B2

        // ---- y2 = relu(y1 @ W2 + b2) ----
        #pragma unroll
        for (int g = 0; g < 2; ++g) {
            const _Float16* yr = Y1row[g];
            h8 p0 = *(const h8*)(yr + q8);
            h8 p1 = *(const h8*)(yr + 32 + q8);
            f4 y = b2v;
            y = MFMA(w2f[0], p0, y);
            y = MFMA(w2f[1], p1, y);
            #pragma unroll
            for (int r = 0; r < 4; ++r) y[r] = fmaxf(y[r], 0.0f);
            store4h(Y2row[g] + wq, y);
        }
        __syncthreads();  // B3

        // ---- x = y2 @ W3 + b3 (all waves, redundantly -> no barrier after) ----
        #pragma unroll
        for (int g = 0; g < 2; ++g) {
            const _Float16* yr = Y2row[g];
            h8 p0 = *(const h8*)(yr + q8);
            h8 p1 = *(const h8*)(yr + 32 + q8);
            f4 x = b3v;
            x = MFMA(w3f[0], p0, x);
            x = MFMA(w3f[1], p1, x);
            if (quad == 0) {
                store4h(a2x[g], x);          // x(t+1) into own a2 staging
                if (wid == 0) {
                    run[g] += x;
                    *(f4*)outp[g] = run[g];  // dwordx4, cumsum output
                }
            }
            outp[g] += SD;
        }
        // stage noise(t+1) into own a2 staging (read next body, same wave)
        store2h(a2n[0], nz0.x, nz0.y);
        store2h(a2n[1], nz1.x, nz1.y);
    };

    #pragma unroll 1
    for (int t = 0; t < STEPS - 1; t += 2) {
        body(0);
        body(1);
    }
    body(0);  // t = 254 (even parity)
}

extern "C" void kernel_launch(void* const* d_in, const int* in_sizes, int n_in,
                              void* d_out, int out_size, void* d_ws, size_t ws_size,
                              hipStream_t stream) {
    genlstm_kernel<<<256, 256, 0, stream>>>(
        (const float*)d_in[0], (const float*)d_in[1], (const float*)d_in[2],
        (const float*)d_in[3], (const float*)d_in[4], (const float*)d_in[5],
        (const float*)d_in[6], (const float*)d_in[7], (const float*)d_in[8],
        (const float*)d_in[9], (float*)d_out);
}

// Round 5
// 408.630 us; speedup vs baseline: 1.2879x; 1.2879x over previous
//
#include <hip/hip_runtime.h>

// GenLSTM: B=8192, T=256 (255 steps), noise=8, seq_dim=4, HID=64, gates=256.
// R5: M=16 rows/block, 512 blocks x 4 waves (2 blocks/CU, 2 waves/SIMD -- R2's
// proven occupancy; R4's 1 wave/SIMD regressed). Keeps R4 wins: swapped-operand
// MFMA (weights in VGPRs as A, state as B -> C^T, packed b64 LDS writes),
// 3 barriers/step, redundant x-phase (no wave0 serialization), wave-private a2
// staging. New: (a) 7-trans cell update (shared denominators + inf-safe clamps)
// vs 10; (b) software pipelining -- gate-h MFMAs for t+1 issued after B3 using
// the SAME h-frags y1 loaded (register reuse, 2 fewer ds_reads), a2-MFMA slice
// completes z at next loop top. LDS ~12.3 KB/block.

typedef _Float16 h8 __attribute__((ext_vector_type(8)));
typedef __fp16 p2h __attribute__((ext_vector_type(2)));
typedef float f4 __attribute__((ext_vector_type(4)));

#define MFMA(a, b, c) __builtin_amdgcn_mfma_f32_16x16x32_f16(a, b, c, 0, 0, 0)

constexpr int SEQ = 256, STEPS = 255, ND = 8, SD = 4, HID = 64, G4 = 256;
constexpr int HST  = 72;  // h/y row stride (f16): 16B-aligned rows
constexpr int A2ST = 24;  // wave-private a2 staging row stride

__device__ __forceinline__ void store4h(_Float16* p, f4 v) {
    p2h lo = __builtin_amdgcn_cvt_pkrtz(v[0], v[1]);
    p2h hi = __builtin_amdgcn_cvt_pkrtz(v[2], v[3]);
    float2 st;
    st.x = __builtin_bit_cast(float, lo);
    st.y = __builtin_bit_cast(float, hi);
    *(float2*)p = st;
}
__device__ __forceinline__ void store2h(_Float16* p, float a, float b_) {
    p2h v = __builtin_amdgcn_cvt_pkrtz(a, b_);
    *(float*)p = __builtin_bit_cast(float, v);
}

__global__ __launch_bounds__(256, 2) void genlstm_kernel(
    const float* __restrict__ noise, const float* __restrict__ Wx,
    const float* __restrict__ Wh, const float* __restrict__ b,
    const float* __restrict__ W1, const float* __restrict__ b1,
    const float* __restrict__ W2, const float* __restrict__ b2,
    const float* __restrict__ W3, const float* __restrict__ b3,
    float* __restrict__ out)
{
    __shared__ alignas(16) _Float16 Hb[2 * 16 * HST];     // [pb][row][HST] h state
    __shared__ alignas(16) _Float16 Y1b[16 * HST];
    __shared__ alignas(16) _Float16 Y2b[16 * HST];
    __shared__ alignas(16) _Float16 A2b[4 * 16 * A2ST];   // [wid][row][A2ST] x|noise
    __shared__ alignas(16) _Float16 Zb[8];                // zeros (a2 quads 2/3)

    const int tid = threadIdx.x, wid = tid >> 6, lane = tid & 63;
    const int col = lane & 15, quad = lane >> 4, q8 = quad * 8;
    const int row0 = blockIdx.x * 16;
    const int n0 = wid * 16 + col;       // hid col for w1/w2 frags
    const int wq = wid * 16 + quad * 4;  // C^T write col base

    // ---- weight frags -> VGPRs ----
    // u index k: [0..63]=h, [64..67]=x, [68..75]=noise, [76..95]=0
    h8 wg[4][3], w1f[2], w2f[2], w3f[2];
    #pragma unroll
    for (int g = 0; g < 4; ++g)
        #pragma unroll
        for (int s = 0; s < 3; ++s)
            #pragma unroll
            for (int j = 0; j < 8; ++j) {
                const int k = 32 * s + q8 + j;
                const int n = 64 * g + n0;
                float v;
                if (k < 64) v = Wh[k * G4 + n];
                else if (k < 76) v = Wx[(k - 64) * G4 + n];
                else v = 0.0f;
                wg[g][s][j] = (_Float16)v;
            }
    #pragma unroll
    for (int s = 0; s < 2; ++s)
        #pragma unroll
        for (int j = 0; j < 8; ++j) {
            const int k = 32 * s + q8 + j;
            w1f[s][j] = (_Float16)W1[k * HID + n0];
            w2f[s][j] = (_Float16)W2[k * HID + n0];
            w3f[s][j] = (_Float16)(col < 4 ? W3[k * SD + col] : 0.0f);
        }
    // biases by OUTPUT index (C^T): n = wq + r
    f4 bzv[4], b1v, b2v, b3v;
    #pragma unroll
    for (int r = 0; r < 4; ++r) {
        #pragma unroll
        for (int g = 0; g < 4; ++g) bzv[g][r] = b[64 * g + wq + r];
        b1v[r] = b1[wq + r];
        b2v[r] = b2[wq + r];
        b3v[r] = (quad == 0) ? b3[r] : 0.0f;
    }

    // ---- LDS init ----
    for (int i = tid; i < 2 * 16 * HST; i += 256) Hb[i] = (_Float16)0;
    for (int i = tid; i < 4 * 16 * A2ST; i += 256) A2b[i] = (_Float16)0;
    if (tid < 8) Zb[tid] = (_Float16)0;
    if (tid < 16) {  // out[:,0,:] = 0
        float4 z; z.x = z.y = z.z = z.w = 0.0f;
        *(float4*)(out + (size_t)(row0 + tid) * SEQ * SD) = z;
    }
    __syncthreads();

    // ---- loop-invariant pointers ----
    const int nrow = lane >> 2, ncc = (lane & 3) * 2;
    const float* nptr = noise + ((size_t)(row0 + nrow) * SEQ) * ND + ncc;
    _Float16* a2n = &A2b[(wid * 16 + nrow) * A2ST + 4 + ncc];
    _Float16* a2x = &A2b[(wid * 16 + col) * A2ST];
    const _Float16* a2rd = (quad < 2) ? &A2b[(wid * 16 + col) * A2ST + 8 * quad] : Zb;
    _Float16* Hrow[2] = { &Hb[col * HST], &Hb[(16 + col) * HST] };
    _Float16* Y1row = &Y1b[col * HST];
    _Float16* Y2row = &Y2b[col * HST];
    float* outp = out + ((size_t)(row0 + col) * SEQ + 1) * SD;

    // stage noise(0); x(0)=0 from zero-init (wave-private, no barrier)
    {
        float2 nz = *(const float2*)nptr;
        store2h(a2n, nz.x, nz.y);
        nptr += ND;
    }

    f4 cst = {0.f, 0.f, 0.f, 0.f}, run = {0.f, 0.f, 0.f, 0.f};
    // gate accumulators persist across iterations; h(0)=0 -> bias only
    f4 zi = bzv[0], zf = bzv[1], zg = bzv[2], zo = bzv[3];
    h8 h0, h1;  // h(t+1) frags, loaded in y1 phase, reused for gate-h MFMAs

    auto body = [&](int pb) {
        // global prefetch of noise(t+1) (t+1 <= 255 always in-bounds)
        float2 nz = *(const float2*)nptr;
        nptr += ND;

        // ---- complete z(t): a2 slice (x|noise staged by this wave last iter) ----
        h8 a2 = *(const h8*)a2rd;
        zi = MFMA(wg[0][2], a2, zi);
        zf = MFMA(wg[1][2], a2, zf);
        zg = MFMA(wg[2][2], a2, zg);
        zo = MFMA(wg[3][2], a2, zo);

        // ---- cell update, 7 transcendentals (shared denom, inf-safe clamps) ----
        f4 hv;
        #pragma unroll
        for (int r = 0; r < 4; ++r) {
            float Ei = __expf(-fmaxf(zi[r], -15.f));
            float Ef = __expf(-fmaxf(zf[r], -15.f));
            float Eg = __expf(-2.f * fmaxf(zg[r], -15.f));
            float Eo = __expf(-zo[r]);
            float Di = 1.f + Ei, Df = 1.f + Ef, Dg = 1.f + Eg, Do = 1.f + Eo;
            float DiDg = Di * Dg;
            // c' = sig(f)c + sig(i)tanh(g) over common denominator Df*Di*Dg
            float cn = (cst[r] * DiDg + (2.f - Dg) * Df) *
                       __builtin_amdgcn_rcpf(Df * DiDg);
            cst[r] = cn;
            float Ec = __expf(-2.f * fmaxf(cn, -15.f));
            hv[r] = (1.f - Ec) * __builtin_amdgcn_rcpf(Do * (1.f + Ec));
        }
        store4h(Hrow[pb ^ 1] + wq, hv);  // h(t+1)
        __syncthreads();  // B1

        // ---- y1 = relu(h(t+1) @ W1 + b1) ----
        const _Float16* hb = Hrow[pb ^ 1];
        h0 = *(const h8*)(hb + q8);
        h1 = *(const h8*)(hb + 32 + q8);
        f4 y1 = b1v;
        y1 = MFMA(w1f[0], h0, y1);
        y1 = MFMA(w1f[1], h1, y1);
        #pragma unroll
        for (int r = 0; r < 4; ++r) y1[r] = fmaxf(y1[r], 0.0f);
        store4h(Y1row + wq, y1);
        __syncthreads();  // B2

        // ---- y2 = relu(y1 @ W2 + b2) ----
        h8 p0 = *(const h8*)(Y1row + q8);
        h8 p1 = *(const h8*)(Y1row + 32 + q8);
        f4 y2 = b2v;
        y2 = MFMA(w2f[0], p0, y2);
        y2 = MFMA(w2f[1], p1, y2);
        #pragma unroll
        for (int r = 0; r < 4; ++r) y2[r] = fmaxf(y2[r], 0.0f);
        store4h(Y2row + wq, y2);
        __syncthreads();  // B3

        // ---- x = y2 @ W3 + b3 (all waves redundantly; quad0 holds real cols) ----
        h8 q0 = *(const h8*)(Y2row + q8);
        h8 q1 = *(const h8*)(Y2row + 32 + q8);
        f4 x = b3v;
        x = MFMA(w3f[0], q0, x);
        x = MFMA(w3f[1], q1, x);

        // ---- software-pipelined gate-h MFMAs for t+1 (h0/h1 reused from y1;
        //      independent of the x chain -> scheduler overlaps them) ----
        zi = bzv[0]; zi = MFMA(wg[0][0], h0, zi); zi = MFMA(wg[0][1], h1, zi);
        zf = bzv[1]; zf = MFMA(wg[1][0], h0, zf); zf = MFMA(wg[1][1], h1, zf);
        zg = bzv[2]; zg = MFMA(wg[2][0], h0, zg); zg = MFMA(wg[2][1], h1, zg);
        zo = bzv[3]; zo = MFMA(wg[3][0], h0, zo); zo = MFMA(wg[3][1], h1, zo);

        if (quad == 0) {
            store4h(a2x, x);             // x(t+1) into own a2 staging
            if (wid == 0) {
                run += x;
                *(f4*)outp = run;        // cumsum output, dwordx4
            }
        }
        store2h(a2n, nz.x, nz.y);        // noise(t+1) into own a2 staging
        outp += SD;
    };

    #pragma unroll 1
    for (int t = 0; t < STEPS - 1; t += 2) {
        body(0);
        body(1);
    }
    body(0);  // t = 254
}

extern "C" void kernel_launch(void* const* d_in, const int* in_sizes, int n_in,
                              void* d_out, int out_size, void* d_ws, size_t ws_size,
                              hipStream_t stream) {
    genlstm_kernel<<<512, 256, 0, stream>>>(
        (const float*)d_in[0], (const float*)d_in[1], (const float*)d_in[2],
        (const float*)d_in[3], (const float*)d_in[4], (const float*)d_in[5],
        (const float*)d_in[6], (const float*)d_in[7], (const float*)d_in[8],
        (const float*)d_in[9], (float*)d_out);
}